// Round 13
// baseline (350.690 us; speedup 1.0000x reference)
//
#include <hip/hip_runtime.h>
#include <math.h>

#define N_NODES 20480
#define T_IN 128
#define F 256
#define HEADS 4
#define HID 64
#define NG 64
#define NCLS 4
#define NEG 0.2f
#define EPS 1e-5f
#define PTR_STRIDE (N_NODES + 64)
#define NBKT 256
#define BKT_NODES 80
#define BKT_CAP 2048
#define ECHUNK 4096
#define NSLOT 32

typedef float f32x4 __attribute__((ext_vector_type(4)));
typedef short s16x8 __attribute__((ext_vector_type(8)));
typedef ushort u16x8 __attribute__((ext_vector_type(8)));

static __device__ __forceinline__ ushort f2bf(float f) {
  union { float f; unsigned u; } a; a.f = f;
  unsigned u = a.u;
  unsigned r = (u + 0x7fffu + ((u >> 16) & 1u)) >> 16;
  return (ushort)r;
}
static __device__ __forceinline__ float bf2f(ushort u) {
  union { unsigned u; float f; } a; a.u = ((unsigned)u) << 16;
  return a.f;
}

// ---------------- bucketed CSR build ----------------
__global__ __launch_bounds__(256) void bucketA_kernel(const int* __restrict__ edge, int E,
                                                      int* __restrict__ bcnt,
                                                      unsigned* __restrict__ bdata) {
  int c = blockIdx.y;
  int tot = E + N_NODES;
  int e0 = blockIdx.x * ECHUNK;
  __shared__ int hist[NBKT];
  __shared__ int base[NBKT];
  int tid = threadIdx.x;
  hist[tid] = 0;
  __syncthreads();
  const int* src = edge + (size_t)c * 2 * E;
  const int* dst = src + E;
  unsigned pk[16];
  int bk[16];
#pragma unroll
  for (int i = 0; i < 16; ++i) {
    int e = e0 + i * 256 + tid;
    if (e < tot) {
      int s, d;
      if (e < E) { s = src[e]; d = dst[e]; } else { s = d = e - E; }
      int b = d / BKT_NODES;
      bk[i] = b;
      pk[i] = (unsigned)s | ((unsigned)(d - b * BKT_NODES) << 16);
      atomicAdd(&hist[b], 1);
    } else bk[i] = -1;
  }
  __syncthreads();
  base[tid] = (hist[tid] > 0) ? atomicAdd(&bcnt[c * NBKT + tid], hist[tid]) : 0;
  hist[tid] = 0;
  __syncthreads();
#pragma unroll
  for (int i = 0; i < 16; ++i) {
    if (bk[i] >= 0) {
      int pos = atomicAdd(&hist[bk[i]], 1) + base[bk[i]];
      if (pos < BKT_CAP)
        bdata[((size_t)(c * NBKT + bk[i])) * BKT_CAP + pos] = pk[i];
    }
  }
}

__global__ void bscan_kernel(const int* __restrict__ bcnt, int* __restrict__ bbase) {
  __shared__ int sh[NBKT];
  int t = threadIdx.x;
  for (int c = 0; c < NCLS; ++c) {
    int v = bcnt[c * NBKT + t];
    sh[t] = v;
    __syncthreads();
    for (int off = 1; off < NBKT; off <<= 1) {
      int u = (t >= off) ? sh[t - off] : 0;
      __syncthreads();
      sh[t] += u;
      __syncthreads();
    }
    bbase[c * NBKT + t] = sh[t] - v;
    __syncthreads();
  }
}

__global__ __launch_bounds__(256) void bucketB_kernel(
    const int* __restrict__ bcnt, const int* __restrict__ bbase,
    const unsigned* __restrict__ bdata, int* __restrict__ ptr4,
    ushort* __restrict__ csr4, int TOT_) {
  int b = blockIdx.x, c = blockIdx.y;
  __shared__ int lcount[BKT_NODES + 1];
  __shared__ int lptr[BKT_NODES + 1];
  __shared__ ushort stage[BKT_CAP];
  int tid = threadIdx.x;
  int cnt = min(bcnt[c * NBKT + b], BKT_CAP);
  int base = bbase[c * NBKT + b];
  const unsigned* bd = bdata + ((size_t)(c * NBKT + b)) * BKT_CAP;
  if (tid <= BKT_NODES) lcount[tid] = 0;
  __syncthreads();
  for (int i = tid; i < cnt; i += 256) atomicAdd(&lcount[bd[i] >> 16], 1);
  __syncthreads();
  if (tid == 0) {
    int acc = 0;
    for (int n = 0; n < BKT_NODES; ++n) { lptr[n] = acc; acc += lcount[n]; }
    lptr[BKT_NODES] = acc;
  }
  __syncthreads();
  if (tid < BKT_NODES) ptr4[c * PTR_STRIDE + b * BKT_NODES + tid] = base + lptr[tid];
  if (b == NBKT - 1 && tid == 0) ptr4[c * PTR_STRIDE + N_NODES] = base + lptr[BKT_NODES];
  if (tid <= BKT_NODES) lcount[tid] = 0;
  __syncthreads();
  for (int i = tid; i < cnt; i += 256) {
    unsigned v = bd[i];
    int ld = v >> 16;
    int p = atomicAdd(&lcount[ld], 1) + lptr[ld];
    stage[p] = (ushort)(v & 0xffffu);
  }
  __syncthreads();
  for (int i = tid; i < cnt; i += 256)
    csr4[(size_t)c * TOT_ + base + i] = stage[i];
}

// ---- combined upfront converts: x->bf16, W1^T->bf16, W2^T->bf16 (one launch) ----
__global__ void prep_kernel(const float* __restrict__ x, ushort* __restrict__ xb,
                            const float* __restrict__ W1, ushort* __restrict__ w1t,
                            const float* __restrict__ W2, ushort* __restrict__ w2t) {
  int bid = blockIdx.x;
  int tid = threadIdx.x;
  if (bid < 2560) {
    int idx = bid * 256 + tid;
    float4 v = *(const float4*)(&x[(size_t)idx * 4]);
    ushort4 o;
    o.x = f2bf(v.x); o.y = f2bf(v.y); o.z = f2bf(v.z); o.w = f2bf(v.w);
    *(ushort4*)(&xb[(size_t)idx * 4]) = o;
  } else if (bid < 3072) {
    int t = bid - 2560;
    int c = t >> 7;
    int idx = (t & 127) * 256 + tid;
    int f = idx / T_IN, k = idx - f * T_IN;
    w1t[(size_t)c * F * T_IN + idx] = f2bf(W1[(size_t)c * T_IN * F + (size_t)k * F + f]);
  } else {
    int t = bid - 3072;
    int c = t >> 8;
    int idx = (t & 255) * 256 + tid;
    int f = idx / F, k = idx - f * F;
    w2t[(size_t)c * F * F + idx] = f2bf(W2[(size_t)c * F * F + (size_t)k * F + f]);
  }
}

// ---- MFMA GEMM (z classes) + fused attn epilogue; NORM: GraphNorm+PReLU on A from slots ----
template <bool NORM>
__global__ __launch_bounds__(256) void gemm4_kernel(
    const ushort* __restrict__ A, size_t aStride,
    const ushort* __restrict__ Bt,
    const float* __restrict__ asrc, const float* __restrict__ adst,
    const float* __restrict__ slots4, const float* __restrict__ nw4,
    const float* __restrict__ nb4, const float* __restrict__ na4,
    const float* __restrict__ np4,
    ushort* __restrict__ C, float* __restrict__ attn4, int K) {
  int z = blockIdx.z;
  const ushort* Ap = A + (size_t)z * aStride;
  const ushort* Btp = Bt + (size_t)z * F * K;
  ushort* Cp = C + (size_t)z * N_NODES * F;
  float* attn_s = attn4 + (size_t)z * 2 * N_NODES * HEADS;
  float* attn_d = attn_s + N_NODES * HEADS;
  const float* asp = asrc + (size_t)z * F;
  const float* adp = adst + (size_t)z * F;

  __shared__ ushort sA[128][72];
  __shared__ ushort sB[128][72];
  __shared__ float sNsc[256];
  __shared__ float sNsh[256];
  int tid = threadIdx.x;
  float p_ = 0.f;
  if constexpr (NORM) {
    const float* sl = slots4 + (size_t)z * 2 * NSLOT * 256;
    float ssum = 0.f, ssq = 0.f;
#pragma unroll 8
    for (int i = 0; i < NSLOT; ++i) {
      ssum += sl[i * 256 + tid];
      ssq += sl[(NSLOT + i) * 256 + tid];
    }
    const float invN = 1.0f / N_NODES;
    float mean = ssum * invN;
    float msq = ssq * invN;
    float av = na4[(size_t)z * F + tid];
    float var = msq - (2.f * av - av * av) * mean * mean;
    float sc = nw4[(size_t)z * F + tid] * rsqrtf(var + EPS);
    sNsc[tid] = sc;
    sNsh[tid] = nb4[(size_t)z * F + tid] - sc * av * mean;
    p_ = np4[z];
    __syncthreads();
  }
  int lane = tid & 63;
  int wave = tid >> 6;
  int wr = (wave >> 1) * 64, wc = (wave & 1) * 64;
  int row0 = blockIdx.x * 128;
  int col0 = blockIdx.y * 128;
  int l15 = lane & 15, l4 = lane >> 4;
  int arow = tid >> 1, aseg = (tid & 1) * 32;
  int bcol = tid & 127, bk = (tid >> 7) * 32;
  f32x4 acc[4][4] = {};
  for (int kt = 0; kt < K; kt += 64) {
    const ushort* ap = Ap + (size_t)(row0 + arow) * K + kt + aseg;
#pragma unroll
    for (int i = 0; i < 4; ++i) {
      if constexpr (NORM) {
        s16x8 av8 = *(const s16x8*)(ap + i * 8);
        s16x8 ov;
#pragma unroll
        for (int kk = 0; kk < 8; ++kk) {
          int col = kt + aseg + i * 8 + kk;
          float xv = bf2f((ushort)av8[kk]);
          float y = xv * sNsc[col] + sNsh[col];
          y = (y >= 0.f) ? y : p_ * y;
          ov[kk] = (short)f2bf(y);
        }
        *(s16x8*)(&sA[arow][aseg + i * 8]) = ov;
      } else {
        *(s16x8*)(&sA[arow][aseg + i * 8]) = *(const s16x8*)(ap + i * 8);
      }
    }
    const ushort* bp = Btp + (size_t)(col0 + bcol) * K + kt + bk;
#pragma unroll
    for (int i = 0; i < 4; ++i)
      *(s16x8*)(&sB[bcol][bk + i * 8]) = *(const s16x8*)(bp + i * 8);
    __syncthreads();
#pragma unroll
    for (int kh = 0; kh < 2; ++kh) {
      s16x8 af[4], bfr[4];
#pragma unroll
      for (int m = 0; m < 4; ++m)
        af[m] = *(const s16x8*)(&sA[wr + m * 16 + l15][kh * 32 + l4 * 8]);
#pragma unroll
      for (int n = 0; n < 4; ++n)
        bfr[n] = *(const s16x8*)(&sB[wc + n * 16 + l15][kh * 32 + l4 * 8]);
#pragma unroll
      for (int m = 0; m < 4; ++m)
#pragma unroll
        for (int n = 0; n < 4; ++n)
          acc[m][n] = __builtin_amdgcn_mfma_f32_16x16x32_bf16(af[m], bfr[n], acc[m][n], 0, 0, 0);
    }
    __syncthreads();
  }

  int hh = (col0 + wc) >> 6;
  float as_n[4], ad_n[4];
#pragma unroll
  for (int n = 0; n < 4; ++n) {
    int cg = col0 + wc + n * 16 + l15;
    as_n[n] = asp[cg];
    ad_n[n] = adp[cg];
  }
#pragma unroll
  for (int m = 0; m < 4; ++m)
#pragma unroll
    for (int r = 0; r < 4; ++r) {
      float ps = acc[m][0][r] * as_n[0] + acc[m][1][r] * as_n[1] +
                 acc[m][2][r] * as_n[2] + acc[m][3][r] * as_n[3];
      float pd = acc[m][0][r] * ad_n[0] + acc[m][1][r] * ad_n[1] +
                 acc[m][2][r] * ad_n[2] + acc[m][3][r] * ad_n[3];
#pragma unroll
      for (int o = 1; o < 16; o <<= 1) {
        ps += __shfl_xor(ps, o);
        pd += __shfl_xor(pd, o);
      }
      if (l15 == 0) {
        int rg = row0 + wr + m * 16 + l4 * 4 + r;
        attn_s[rg * HEADS + hh] = ps;
        attn_d[rg * HEADS + hh] = pd;
      }
    }

#pragma unroll
  for (int m = 0; m < 4; ++m)
#pragma unroll
    for (int n = 0; n < 4; ++n) {
      int rg = row0 + wr + m * 16 + l4 * 4;
      int cg = col0 + wc + n * 16 + l15;
#pragma unroll
      for (int r = 0; r < 4; ++r)
        Cp[(size_t)(rg + r) * F + cg] = f2bf(acc[m][n][r]);
    }
}

// ---- softmax + aggregation + fused block-level column stats (no LDS atomics) ----
__global__ __launch_bounds__(256) void agg8_kernel(
    const ushort* __restrict__ hfeat4, const float* __restrict__ attn4,
    const int* __restrict__ ptr4, const ushort* __restrict__ csr4,
    const float* __restrict__ bias4, ushort* __restrict__ out4,
    float* __restrict__ slots4, int TOT_) {
  __shared__ float w_lds[4][64][4];
  __shared__ int s_lds[4][64];
  __shared__ float st_sum[4][256];
  __shared__ float st_sq[4][256];
  int z = blockIdx.y;
  int tid = threadIdx.x;
  int wave = tid >> 6, lane = tid & 63;
  int node = blockIdx.x * 4 + wave;
  const ushort* hfeat = hfeat4 + (size_t)z * N_NODES * F;
  const float* attn_s = attn4 + (size_t)z * 2 * N_NODES * HEADS;
  const float* attn_d = attn_s + N_NODES * HEADS;
  const int* ptr = ptr4 + (size_t)z * PTR_STRIDE;
  const ushort* csr = csr4 + (size_t)z * TOT_;
  int beg = ptr[node];
  int deg = ptr[node + 1] - beg;
  float4 ad = *(const float4*)(&attn_d[node * 4]);

  int half = lane >> 5, li = lane & 31;
  int ch0 = li * 8;
  int head = li >> 3;
  float acc[8] = {0.f, 0.f, 0.f, 0.f, 0.f, 0.f, 0.f, 0.f};
  float4 dsum = make_float4(0.f, 0.f, 0.f, 0.f);

  for (int c0 = 0; c0 < deg; c0 += 64) {
    int cnt = min(64, deg - c0);
    float4 wv = make_float4(0.f, 0.f, 0.f, 0.f);
    int sE = 0;
    if (c0 + lane < deg) {
      sE = csr[beg + c0 + lane];
      float4 as = *(const float4*)(&attn_s[sE * 4]);
      float vx = as.x + ad.x, vy = as.y + ad.y, vz = as.z + ad.z, vw = as.w + ad.w;
      vx = (vx >= 0.f) ? vx : NEG * vx;
      vy = (vy >= 0.f) ? vy : NEG * vy;
      vz = (vz >= 0.f) ? vz : NEG * vz;
      vw = (vw >= 0.f) ? vw : NEG * vw;
      wv.x = __expf(vx); wv.y = __expf(vy);
      wv.z = __expf(vz); wv.w = __expf(vw);
    }
    dsum.x += wv.x; dsum.y += wv.y; dsum.z += wv.z; dsum.w += wv.w;
    s_lds[wave][lane] = sE;
    *(float4*)(&w_lds[wave][lane][0]) = wv;

    int cpad = (cnt + 1) & ~1;
    for (int e = half; e < cpad; e += 2) {
      int s = s_lds[wave][e];
      float w = w_lds[wave][e][head];
      u16x8 hv = *(const u16x8*)(&hfeat[(size_t)s * F + ch0]);
#pragma unroll
      for (int k = 0; k < 8; ++k) acc[k] += w * bf2f(hv[k]);
    }
  }
#pragma unroll
  for (int o = 1; o < 64; o <<= 1) {
    dsum.x += __shfl_xor(dsum.x, o);
    dsum.y += __shfl_xor(dsum.y, o);
    dsum.z += __shfl_xor(dsum.z, o);
    dsum.w += __shfl_xor(dsum.w, o);
  }
#pragma unroll
  for (int k = 0; k < 8; ++k) acc[k] += __shfl_xor(acc[k], 32);

  if (half == 0) {
    float dh = (head == 0) ? dsum.x : (head == 1) ? dsum.y : (head == 2) ? dsum.z : dsum.w;
    float inv = 1.f / (dh + 1e-16f);
    u16x8 o;
#pragma unroll
    for (int k = 0; k < 8; ++k) {
      ushort rb = f2bf(acc[k] * inv + bias4[(size_t)z * F + ch0 + k]);
      o[k] = rb;
      float rf = bf2f(rb);            // stats on the stored bf16 value (matches stats4 path)
      st_sum[wave][ch0 + k] = rf;
      st_sq[wave][ch0 + k] = rf * rf;
    }
    *(u16x8*)(&out4[((size_t)z * N_NODES + node) * F + ch0]) = o;
  }
  __syncthreads();
  // cross-wave tree add (plain reads, no atomics) + one global atomic per channel
  float s = st_sum[0][tid] + st_sum[1][tid] + st_sum[2][tid] + st_sum[3][tid];
  float q = st_sq[0][tid] + st_sq[1][tid] + st_sq[2][tid] + st_sq[3][tid];
  int slot = blockIdx.x & (NSLOT - 1);
  float* sl = slots4 + (size_t)z * 2 * NSLOT * 256;
  atomicAdd(&sl[slot * 256 + tid], s);
  atomicAdd(&sl[(NSLOT + slot) * 256 + tid], q);
}

// ---------------- fused GraphNorm (from slots) + PReLU + mean pool ----------------
__device__ __forceinline__ int lower_bound_dev(const int* __restrict__ arr, int n, int key) {
  int lo = 0, hi = n;
  while (lo < hi) {
    int mid = (lo + hi) >> 1;
    if (arr[mid] < key) lo = mid + 1; else hi = mid;
  }
  return lo;
}

__global__ void pool_norm4_kernel(const ushort* __restrict__ x4, const int* __restrict__ batch4,
                                  const float* __restrict__ slots4, const float* __restrict__ w4,
                                  const float* __restrict__ b4, const float* __restrict__ a4,
                                  const float* __restrict__ p4, float* __restrict__ g_pool4,
                                  float* __restrict__ g_cnt4) {
  int z = blockIdx.y;
  int gb = blockIdx.x >> 2, part = blockIdx.x & 3;
  int tid = threadIdx.x;
  const ushort* x = x4 + (size_t)z * N_NODES * F;
  const int* batch = batch4 + (size_t)z * N_NODES;
  const float* sl = slots4 + (size_t)z * 2 * NSLOT * 256;
  float ssum = 0.f, ssq = 0.f;
#pragma unroll 8
  for (int i = 0; i < NSLOT; ++i) {
    ssum += sl[i * 256 + tid];
    ssq += sl[(NSLOT + i) * 256 + tid];
  }
  int lo = lower_bound_dev(batch, N_NODES, gb);
  int hi = lower_bound_dev(batch, N_NODES, gb + 1);
  const float invN = 1.0f / N_NODES;
  float mean = ssum * invN, msq = ssq * invN;
  float av = a4[(size_t)z * F + tid];
  float var = msq - (2.f * av - av * av) * mean * mean;
  float sc = w4[(size_t)z * F + tid] * rsqrtf(var + EPS);
  float bb = b4[(size_t)z * F + tid];
  float p = p4[z];
  float s = 0.f;
  for (int n = lo + part; n < hi; n += 4) {
    float v = bf2f(x[(size_t)n * F + tid]);
    float y = (v - av * mean) * sc + bb;
    s += (y >= 0.f) ? y : p * y;
  }
  atomicAdd(&g_pool4[((size_t)z * NG + gb) * F + tid], s);
  if (part == 0 && tid == 0) g_cnt4[z * NG + gb] = (float)(hi - lo);
}

// ---------------- conv1d(k=4,s=4) + avgpool(4) ----------------
__global__ void down4_kernel(const float* __restrict__ g_pool4, const float* __restrict__ g_cnt4,
                             const float* __restrict__ cw4, const float* __restrict__ cb4,
                             float* __restrict__ out, int cls0) {
  int z = blockIdx.y;
  int tid = blockIdx.x * blockDim.x + threadIdx.x;
  if (tid >= NG * 16) return;
  int ng = tid >> 4, o = tid & 15;
  const float* g = g_pool4 + ((size_t)z * NG + ng) * F;
  float inv = 1.f / fmaxf(g_cnt4[z * NG + ng], 1.f);
  const float* cw = cw4 + (size_t)z * 4;
  float cb0 = cb4[z];
  float w0 = cw[0], w1 = cw[1], w2 = cw[2], w3 = cw[3];
  float acc = 0.f;
#pragma unroll
  for (int q = 0; q < 4; ++q) {
    const float* gp = g + (o * 4 + q) * 4;
    acc += cb0 + (gp[0] * w0 + gp[1] * w1 + gp[2] * w2 + gp[3] * w3) * inv;
  }
  out[ng * (NCLS * 16) + (cls0 + z) * 16 + o] = acc * 0.25f;
}

extern "C" void kernel_launch(void* const* d_in, const int* in_sizes, int n_in,
                              void* d_out, int out_size, void* d_ws, size_t ws_size,
                              hipStream_t stream) {
  const float* x       = (const float*)d_in[0];
  const int*   edge    = (const int*)d_in[1];
  const int*   batch   = (const int*)d_in[2];
  const float* W1      = (const float*)d_in[3];
  const float* a_src1  = (const float*)d_in[4];
  const float* a_dst1  = (const float*)d_in[5];
  const float* b1      = (const float*)d_in[6];
  const float* W2      = (const float*)d_in[7];
  const float* a_src2  = (const float*)d_in[8];
  const float* a_dst2  = (const float*)d_in[9];
  const float* b2      = (const float*)d_in[10];
  const float* gn_w1   = (const float*)d_in[11];
  const float* gn_b1   = (const float*)d_in[12];
  const float* gn_a1   = (const float*)d_in[13];
  const float* gn_w2   = (const float*)d_in[14];
  const float* gn_b2   = (const float*)d_in[15];
  const float* gn_a2   = (const float*)d_in[16];
  const float* prelu1  = (const float*)d_in[17];
  const float* prelu2  = (const float*)d_in[18];
  const float* conv_w  = (const float*)d_in[19];
  const float* conv_b  = (const float*)d_in[20];
  float* out = (float*)d_out;

  const int E   = in_sizes[1] / (NCLS * 2);
  const int TOT = E + N_NODES;

  auto rb = [](size_t b) -> size_t { return (b + 255) / 256 * 256; };
  auto need = [&](int zw) -> size_t {
    return rb((size_t)N_NODES * T_IN * 2)
         + rb((size_t)zw * N_NODES * F * 2)
         + rb((size_t)zw * N_NODES * F * 2)
         + rb((size_t)NCLS * F * T_IN * 2)
         + rb((size_t)NCLS * F * F * 2)
         + rb((size_t)zw * 2 * N_NODES * HEADS * 4)
         + rb((size_t)NCLS * NBKT * 4)
         + rb((size_t)NCLS * NBKT * 4)
         + rb((size_t)2 * NCLS * 2 * NSLOT * 256 * 4)   // slots L1+L2
         + rb((size_t)NCLS * NG * F * 4)
         + rb((size_t)NCLS * NG * 4)
         + rb((size_t)NCLS * PTR_STRIDE * 4)
         + rb((size_t)NCLS * TOT * 2);
  };
  const int zw = (ws_size >= need(4)) ? 4 : 2;

  char* ws = (char*)d_ws;
  size_t off = 0;
  auto alloc = [&](size_t bytes) -> char* {
    char* p = ws + off;
    off += (bytes + 255) / 256 * 256;
    return p;
  };
  ushort* xb      = (ushort*)alloc((size_t)N_NODES * T_IN * 2);
  ushort* hA      = (ushort*)alloc((size_t)zw * N_NODES * F * 2);
  ushort* hB      = (ushort*)alloc((size_t)zw * N_NODES * F * 2);
  ushort* w1t     = (ushort*)alloc((size_t)NCLS * F * T_IN * 2);
  ushort* w2t     = (ushort*)alloc((size_t)NCLS * F * F * 2);
  float*  attn4   = (float*)alloc((size_t)zw * 2 * N_NODES * HEADS * 4);
  char*   zbeg    = ws + off;
  int*    bcnt    = (int*)alloc((size_t)NCLS * NBKT * 4);
  int*    bbase   = (int*)alloc((size_t)NCLS * NBKT * 4);
  float*  slotsL1 = (float*)alloc((size_t)NCLS * 2 * NSLOT * 256 * 4);
  float*  slotsL2 = (float*)alloc((size_t)NCLS * 2 * NSLOT * 256 * 4);
  float*  g_pool4 = (float*)alloc((size_t)NCLS * NG * F * 4);
  float*  g_cnt4  = (float*)alloc((size_t)NCLS * NG * 4);
  size_t  zlen    = (size_t)((ws + off) - zbeg);
  int* ptr4       = (int*)alloc((size_t)NCLS * PTR_STRIDE * 4);
  ushort* csr4    = (ushort*)alloc((size_t)NCLS * TOT * 2);
  unsigned* bdata = (unsigned*)hA;   // aliases hA (lifetime-disjoint)
  (void)n_in; (void)out_size;

  // ---- upfront: one prep kernel + one memset + CSR build ----
  prep_kernel<<<4096, 256, 0, stream>>>(x, xb, W1, w1t, W2, w2t);
  hipMemsetAsync(zbeg, 0, zlen, stream);
  bucketA_kernel<<<dim3((TOT + ECHUNK - 1) / ECHUNK, NCLS), 256, 0, stream>>>(edge, E, bcnt, bdata);
  bscan_kernel<<<1, NBKT, 0, stream>>>(bcnt, bbase);
  bucketB_kernel<<<dim3(NBKT, NCLS), 256, 0, stream>>>(bcnt, bbase, bdata, ptr4, csr4, TOT);

  const dim3 gemm_grid(N_NODES / 128, 2, zw);
  const dim3 agg_grid(N_NODES / 4, zw);
  const dim3 pool_grid(NG * 4, zw);
  const dim3 down_grid(4, zw);

  for (int it = 0; it < NCLS / zw; ++it) {
    int cls0 = it * zw;
    const int* ptrp = ptr4 + (size_t)cls0 * PTR_STRIDE;
    const ushort* csrp = csr4 + (size_t)cls0 * TOT;
    float* sl1 = slotsL1 + (size_t)cls0 * 2 * NSLOT * 256;
    float* sl2 = slotsL2 + (size_t)cls0 * 2 * NSLOT * 256;

    // ---- layer 1 ----
    gemm4_kernel<false><<<gemm_grid, 256, 0, stream>>>(
        xb, 0, w1t + (size_t)cls0 * F * T_IN,
        a_src1 + (size_t)cls0 * F, a_dst1 + (size_t)cls0 * F,
        nullptr, nullptr, nullptr, nullptr, nullptr, hA, attn4, T_IN);
    agg8_kernel<<<agg_grid, 256, 0, stream>>>(hA, attn4, ptrp, csrp,
                                              b1 + (size_t)cls0 * F, hB, sl1, TOT);

    // ---- layer 2 (GraphNorm+PReLU fused into A-staging, stats from slots) ----
    gemm4_kernel<true><<<gemm_grid, 256, 0, stream>>>(
        hB, (size_t)N_NODES * F, w2t + (size_t)cls0 * F * F,
        a_src2 + (size_t)cls0 * F, a_dst2 + (size_t)cls0 * F,
        sl1, gn_w1 + (size_t)cls0 * F,
        gn_b1 + (size_t)cls0 * F, gn_a1 + (size_t)cls0 * F, prelu1 + cls0,
        hA, attn4, F);
    agg8_kernel<<<agg_grid, 256, 0, stream>>>(hA, attn4, ptrp, csrp,
                                              b2 + (size_t)cls0 * F, hB, sl2, TOT);

    // ---- pool (GraphNorm from slots) + down ----
    pool_norm4_kernel<<<pool_grid, 256, 0, stream>>>(
        hB, batch + (size_t)cls0 * N_NODES, sl2,
        gn_w2 + (size_t)cls0 * F, gn_b2 + (size_t)cls0 * F, gn_a2 + (size_t)cls0 * F,
        prelu2 + cls0, g_pool4 + (size_t)cls0 * NG * F, g_cnt4 + cls0 * NG);
    down4_kernel<<<down_grid, 256, 0, stream>>>(
        g_pool4 + (size_t)cls0 * NG * F, g_cnt4 + cls0 * NG,
        conv_w + (size_t)cls0 * 4, conv_b + cls0, out, cls0);
  }
}

// Round 14
// 339.759 us; speedup vs baseline: 1.0322x; 1.0322x over previous
//
#include <hip/hip_runtime.h>
#include <math.h>

#define N_NODES 20480
#define T_IN 128
#define F 256
#define HEADS 4
#define HID 64
#define NG 64
#define NCLS 4
#define NEG 0.2f
#define EPS 1e-5f
#define PTR_STRIDE (N_NODES + 64)
#define NBKT 256
#define BKT_NODES 80
#define BKT_CAP 2048
#define ECHUNK 4096

typedef float f32x4 __attribute__((ext_vector_type(4)));
typedef short s16x8 __attribute__((ext_vector_type(8)));
typedef ushort u16x8 __attribute__((ext_vector_type(8)));

static __device__ __forceinline__ ushort f2bf(float f) {
  union { float f; unsigned u; } a; a.f = f;
  unsigned u = a.u;
  unsigned r = (u + 0x7fffu + ((u >> 16) & 1u)) >> 16;
  return (ushort)r;
}
static __device__ __forceinline__ float bf2f(ushort u) {
  union { unsigned u; float f; } a; a.u = ((unsigned)u) << 16;
  return a.f;
}

// ---------------- bucketed CSR build ----------------
__global__ __launch_bounds__(256) void bucketA_kernel(const int* __restrict__ edge, int E,
                                                      int* __restrict__ bcnt,
                                                      unsigned* __restrict__ bdata) {
  int c = blockIdx.y;
  int tot = E + N_NODES;
  int e0 = blockIdx.x * ECHUNK;
  __shared__ int hist[NBKT];
  __shared__ int base[NBKT];
  int tid = threadIdx.x;
  hist[tid] = 0;
  __syncthreads();
  const int* src = edge + (size_t)c * 2 * E;
  const int* dst = src + E;
  unsigned pk[16];
  int bk[16];
#pragma unroll
  for (int i = 0; i < 16; ++i) {
    int e = e0 + i * 256 + tid;
    if (e < tot) {
      int s, d;
      if (e < E) { s = src[e]; d = dst[e]; } else { s = d = e - E; }
      int b = d / BKT_NODES;
      bk[i] = b;
      pk[i] = (unsigned)s | ((unsigned)(d - b * BKT_NODES) << 16);
      atomicAdd(&hist[b], 1);
    } else bk[i] = -1;
  }
  __syncthreads();
  base[tid] = (hist[tid] > 0) ? atomicAdd(&bcnt[c * NBKT + tid], hist[tid]) : 0;
  hist[tid] = 0;
  __syncthreads();
#pragma unroll
  for (int i = 0; i < 16; ++i) {
    if (bk[i] >= 0) {
      int pos = atomicAdd(&hist[bk[i]], 1) + base[bk[i]];
      if (pos < BKT_CAP)
        bdata[((size_t)(c * NBKT + bk[i])) * BKT_CAP + pos] = pk[i];
    }
  }
}

__global__ void bscan_kernel(const int* __restrict__ bcnt, int* __restrict__ bbase) {
  __shared__ int sh[NBKT];
  int t = threadIdx.x;
  for (int c = 0; c < NCLS; ++c) {
    int v = bcnt[c * NBKT + t];
    sh[t] = v;
    __syncthreads();
    for (int off = 1; off < NBKT; off <<= 1) {
      int u = (t >= off) ? sh[t - off] : 0;
      __syncthreads();
      sh[t] += u;
      __syncthreads();
    }
    bbase[c * NBKT + t] = sh[t] - v;
    __syncthreads();
  }
}

__global__ __launch_bounds__(256) void bucketB_kernel(
    const int* __restrict__ bcnt, const int* __restrict__ bbase,
    const unsigned* __restrict__ bdata, int* __restrict__ ptr4,
    ushort* __restrict__ csr4, int TOT_) {
  int b = blockIdx.x, c = blockIdx.y;
  __shared__ int lcount[BKT_NODES + 1];
  __shared__ int lptr[BKT_NODES + 1];
  __shared__ ushort stage[BKT_CAP];
  int tid = threadIdx.x;
  int cnt = min(bcnt[c * NBKT + b], BKT_CAP);
  int base = bbase[c * NBKT + b];
  const unsigned* bd = bdata + ((size_t)(c * NBKT + b)) * BKT_CAP;
  if (tid <= BKT_NODES) lcount[tid] = 0;
  __syncthreads();
  for (int i = tid; i < cnt; i += 256) atomicAdd(&lcount[bd[i] >> 16], 1);
  __syncthreads();
  if (tid == 0) {
    int acc = 0;
    for (int n = 0; n < BKT_NODES; ++n) { lptr[n] = acc; acc += lcount[n]; }
    lptr[BKT_NODES] = acc;
  }
  __syncthreads();
  if (tid < BKT_NODES) ptr4[c * PTR_STRIDE + b * BKT_NODES + tid] = base + lptr[tid];
  if (b == NBKT - 1 && tid == 0) ptr4[c * PTR_STRIDE + N_NODES] = base + lptr[BKT_NODES];
  if (tid <= BKT_NODES) lcount[tid] = 0;
  __syncthreads();
  for (int i = tid; i < cnt; i += 256) {
    unsigned v = bd[i];
    int ld = v >> 16;
    int p = atomicAdd(&lcount[ld], 1) + lptr[ld];
    stage[p] = (ushort)(v & 0xffffu);
  }
  __syncthreads();
  for (int i = tid; i < cnt; i += 256)
    csr4[(size_t)c * TOT_ + base + i] = stage[i];
}

// ---- combined upfront converts: x->bf16, W1^T->bf16, W2^T->bf16 (one launch) ----
__global__ void prep_kernel(const float* __restrict__ x, ushort* __restrict__ xb,
                            const float* __restrict__ W1, ushort* __restrict__ w1t,
                            const float* __restrict__ W2, ushort* __restrict__ w2t) {
  int bid = blockIdx.x;
  int tid = threadIdx.x;
  if (bid < 2560) {
    int idx = bid * 256 + tid;
    float4 v = *(const float4*)(&x[(size_t)idx * 4]);
    ushort4 o;
    o.x = f2bf(v.x); o.y = f2bf(v.y); o.z = f2bf(v.z); o.w = f2bf(v.w);
    *(ushort4*)(&xb[(size_t)idx * 4]) = o;
  } else if (bid < 3072) {
    int t = bid - 2560;
    int c = t >> 7;
    int idx = (t & 127) * 256 + tid;
    int f = idx / T_IN, k = idx - f * T_IN;
    w1t[(size_t)c * F * T_IN + idx] = f2bf(W1[(size_t)c * T_IN * F + (size_t)k * F + f]);
  } else {
    int t = bid - 3072;
    int c = t >> 8;
    int idx = (t & 255) * 256 + tid;
    int f = idx / F, k = idx - f * F;
    w2t[(size_t)c * F * F + idx] = f2bf(W2[(size_t)c * F * F + (size_t)k * F + f]);
  }
}

// ---- MFMA GEMM (z classes) + fused attn epilogue; NORM: fused GraphNorm+PReLU on A ----
template <bool NORM>
__global__ __launch_bounds__(256) void gemm4_kernel(
    const ushort* __restrict__ A, size_t aStride,
    const ushort* __restrict__ Bt,
    const float* __restrict__ asrc, const float* __restrict__ adst,
    const float* __restrict__ cst4, const float* __restrict__ nw4,
    const float* __restrict__ nb4, const float* __restrict__ na4,
    const float* __restrict__ np4,
    ushort* __restrict__ C, float* __restrict__ attn4, int K) {
  int z = blockIdx.z;
  const ushort* Ap = A + (size_t)z * aStride;
  const ushort* Btp = Bt + (size_t)z * F * K;
  ushort* Cp = C + (size_t)z * N_NODES * F;
  float* attn_s = attn4 + (size_t)z * 2 * N_NODES * HEADS;
  float* attn_d = attn_s + N_NODES * HEADS;
  const float* asp = asrc + (size_t)z * F;
  const float* adp = adst + (size_t)z * F;

  __shared__ ushort sA[128][72];
  __shared__ ushort sB[128][72];
  __shared__ float sNsc[256];
  __shared__ float sNsh[256];
  int tid = threadIdx.x;
  float p_ = 0.f;
  if constexpr (NORM) {
    const float* cst = cst4 + (size_t)z * 2 * F;
    const float invN = 1.0f / N_NODES;
    float mean = cst[tid] * invN;
    float msq = cst[F + tid] * invN;
    float av = na4[(size_t)z * F + tid];
    float var = msq - (2.f * av - av * av) * mean * mean;
    float sc = nw4[(size_t)z * F + tid] * rsqrtf(var + EPS);
    sNsc[tid] = sc;
    sNsh[tid] = nb4[(size_t)z * F + tid] - sc * av * mean;
    p_ = np4[z];
    __syncthreads();
  }
  int lane = tid & 63;
  int wave = tid >> 6;
  int wr = (wave >> 1) * 64, wc = (wave & 1) * 64;
  int row0 = blockIdx.x * 128;
  int col0 = blockIdx.y * 128;
  int l15 = lane & 15, l4 = lane >> 4;
  int arow = tid >> 1, aseg = (tid & 1) * 32;
  int bcol = tid & 127, bk = (tid >> 7) * 32;
  f32x4 acc[4][4] = {};
  for (int kt = 0; kt < K; kt += 64) {
    const ushort* ap = Ap + (size_t)(row0 + arow) * K + kt + aseg;
#pragma unroll
    for (int i = 0; i < 4; ++i) {
      if constexpr (NORM) {
        s16x8 av8 = *(const s16x8*)(ap + i * 8);
        s16x8 ov;
#pragma unroll
        for (int kk = 0; kk < 8; ++kk) {
          int col = kt + aseg + i * 8 + kk;
          float xv = bf2f((ushort)av8[kk]);
          float y = xv * sNsc[col] + sNsh[col];
          y = (y >= 0.f) ? y : p_ * y;
          ov[kk] = (short)f2bf(y);
        }
        *(s16x8*)(&sA[arow][aseg + i * 8]) = ov;
      } else {
        *(s16x8*)(&sA[arow][aseg + i * 8]) = *(const s16x8*)(ap + i * 8);
      }
    }
    const ushort* bp = Btp + (size_t)(col0 + bcol) * K + kt + bk;
#pragma unroll
    for (int i = 0; i < 4; ++i)
      *(s16x8*)(&sB[bcol][bk + i * 8]) = *(const s16x8*)(bp + i * 8);
    __syncthreads();
#pragma unroll
    for (int kh = 0; kh < 2; ++kh) {
      s16x8 af[4], bfr[4];
#pragma unroll
      for (int m = 0; m < 4; ++m)
        af[m] = *(const s16x8*)(&sA[wr + m * 16 + l15][kh * 32 + l4 * 8]);
#pragma unroll
      for (int n = 0; n < 4; ++n)
        bfr[n] = *(const s16x8*)(&sB[wc + n * 16 + l15][kh * 32 + l4 * 8]);
#pragma unroll
      for (int m = 0; m < 4; ++m)
#pragma unroll
        for (int n = 0; n < 4; ++n)
          acc[m][n] = __builtin_amdgcn_mfma_f32_16x16x32_bf16(af[m], bfr[n], acc[m][n], 0, 0, 0);
    }
    __syncthreads();
  }

  int hh = (col0 + wc) >> 6;
  float as_n[4], ad_n[4];
#pragma unroll
  for (int n = 0; n < 4; ++n) {
    int cg = col0 + wc + n * 16 + l15;
    as_n[n] = asp[cg];
    ad_n[n] = adp[cg];
  }
#pragma unroll
  for (int m = 0; m < 4; ++m)
#pragma unroll
    for (int r = 0; r < 4; ++r) {
      float ps = acc[m][0][r] * as_n[0] + acc[m][1][r] * as_n[1] +
                 acc[m][2][r] * as_n[2] + acc[m][3][r] * as_n[3];
      float pd = acc[m][0][r] * ad_n[0] + acc[m][1][r] * ad_n[1] +
                 acc[m][2][r] * ad_n[2] + acc[m][3][r] * ad_n[3];
#pragma unroll
      for (int o = 1; o < 16; o <<= 1) {
        ps += __shfl_xor(ps, o);
        pd += __shfl_xor(pd, o);
      }
      if (l15 == 0) {
        int rg = row0 + wr + m * 16 + l4 * 4 + r;
        attn_s[rg * HEADS + hh] = ps;
        attn_d[rg * HEADS + hh] = pd;
      }
    }

#pragma unroll
  for (int m = 0; m < 4; ++m)
#pragma unroll
    for (int n = 0; n < 4; ++n) {
      int rg = row0 + wr + m * 16 + l4 * 4;
      int cg = col0 + wc + n * 16 + l15;
#pragma unroll
      for (int r = 0; r < 4; ++r)
        Cp[(size_t)(rg + r) * F + cg] = f2bf(acc[m][n][r]);
    }
}

// ---- softmax (no max pass; logits are tiny) + aggregation: wave per node ----
__global__ __launch_bounds__(256) void agg7_kernel(
    const ushort* __restrict__ hfeat4, const float* __restrict__ attn4,
    const int* __restrict__ ptr4, const ushort* __restrict__ csr4,
    const float* __restrict__ bias4, ushort* __restrict__ out4, int TOT_) {
  __shared__ float w_lds[4][64][4];
  __shared__ int s_lds[4][64];
  int z = blockIdx.y;
  int wave = threadIdx.x >> 6, lane = threadIdx.x & 63;
  int node = blockIdx.x * 4 + wave;
  const ushort* hfeat = hfeat4 + (size_t)z * N_NODES * F;
  const float* attn_s = attn4 + (size_t)z * 2 * N_NODES * HEADS;
  const float* attn_d = attn_s + N_NODES * HEADS;
  const int* ptr = ptr4 + (size_t)z * PTR_STRIDE;
  const ushort* csr = csr4 + (size_t)z * TOT_;
  int beg = ptr[node];
  int deg = ptr[node + 1] - beg;
  float4 ad = *(const float4*)(&attn_d[node * 4]);

  int half = lane >> 5, li = lane & 31;
  int ch0 = li * 8;
  int head = li >> 3;
  float acc[8] = {0.f, 0.f, 0.f, 0.f, 0.f, 0.f, 0.f, 0.f};
  float4 dsum = make_float4(0.f, 0.f, 0.f, 0.f);

  for (int c0 = 0; c0 < deg; c0 += 64) {
    int cnt = min(64, deg - c0);
    float4 wv = make_float4(0.f, 0.f, 0.f, 0.f);
    int sE = 0;
    if (c0 + lane < deg) {
      sE = csr[beg + c0 + lane];
      float4 as = *(const float4*)(&attn_s[sE * 4]);
      float vx = as.x + ad.x, vy = as.y + ad.y, vz = as.z + ad.z, vw = as.w + ad.w;
      vx = (vx >= 0.f) ? vx : NEG * vx;
      vy = (vy >= 0.f) ? vy : NEG * vy;
      vz = (vz >= 0.f) ? vz : NEG * vz;
      vw = (vw >= 0.f) ? vw : NEG * vw;
      wv.x = __expf(vx); wv.y = __expf(vy);
      wv.z = __expf(vz); wv.w = __expf(vw);
    }
    dsum.x += wv.x; dsum.y += wv.y; dsum.z += wv.z; dsum.w += wv.w;
    s_lds[wave][lane] = sE;
    *(float4*)(&w_lds[wave][lane][0]) = wv;   // zero weight for inactive lanes

    int cpad = (cnt + 1) & ~1;
    for (int e = half; e < cpad; e += 2) {    // half-wave per edge, full 512B row
      int s = s_lds[wave][e];
      float w = w_lds[wave][e][head];
      u16x8 hv = *(const u16x8*)(&hfeat[(size_t)s * F + ch0]);
#pragma unroll
      for (int k = 0; k < 8; ++k) acc[k] += w * bf2f(hv[k]);
    }
  }
#pragma unroll
  for (int o = 1; o < 64; o <<= 1) {
    dsum.x += __shfl_xor(dsum.x, o);
    dsum.y += __shfl_xor(dsum.y, o);
    dsum.z += __shfl_xor(dsum.z, o);
    dsum.w += __shfl_xor(dsum.w, o);
  }
#pragma unroll
  for (int k = 0; k < 8; ++k) acc[k] += __shfl_xor(acc[k], 32);

  if (half == 0) {
    float dh = (head == 0) ? dsum.x : (head == 1) ? dsum.y : (head == 2) ? dsum.z : dsum.w;
    float inv = 1.f / (dh + 1e-16f);
    u16x8 o;
#pragma unroll
    for (int k = 0; k < 8; ++k)
      o[k] = f2bf(acc[k] * inv + bias4[(size_t)z * F + ch0 + k]);
    *(u16x8*)(&out4[((size_t)z * N_NODES + node) * F + ch0]) = o;
  }
}

// ---------------- GraphNorm stats (bf16 input) ----------------
__global__ void stats4_kernel(const ushort* __restrict__ x4, float* __restrict__ colstat) {
  int z = blockIdx.y;
  const ushort* x = x4 + (size_t)z * N_NODES * F;
  float* cs = colstat + (size_t)z * 2 * F;
  float* cq = cs + F;
  int tid = threadIdx.x;
  int rbeg = blockIdx.x * 128;
  float s = 0.f, s2 = 0.f;
  for (int r = 0; r < 128; ++r) {
    float v = bf2f(x[(size_t)(rbeg + r) * F + tid]);
    s += v;
    s2 += v * v;
  }
  atomicAdd(&cs[tid], s);
  atomicAdd(&cq[tid], s2);
}

// ---------------- fused GraphNorm + PReLU + mean pool ----------------
__device__ __forceinline__ int lower_bound_dev(const int* __restrict__ arr, int n, int key) {
  int lo = 0, hi = n;
  while (lo < hi) {
    int mid = (lo + hi) >> 1;
    if (arr[mid] < key) lo = mid + 1; else hi = mid;
  }
  return lo;
}

__global__ void pool_norm4_kernel(const ushort* __restrict__ x4, const int* __restrict__ batch4,
                                  const float* __restrict__ colstat, const float* __restrict__ w4,
                                  const float* __restrict__ b4, const float* __restrict__ a4,
                                  const float* __restrict__ p4, float* __restrict__ g_pool4,
                                  float* __restrict__ g_cnt4) {
  int z = blockIdx.y;
  int gb = blockIdx.x >> 2, part = blockIdx.x & 3;
  int tid = threadIdx.x;
  const ushort* x = x4 + (size_t)z * N_NODES * F;
  const int* batch = batch4 + (size_t)z * N_NODES;
  const float* cs = colstat + (size_t)z * 2 * F;
  const float* cq = cs + F;
  int lo = lower_bound_dev(batch, N_NODES, gb);
  int hi = lower_bound_dev(batch, N_NODES, gb + 1);
  const float invN = 1.0f / N_NODES;
  float mean = cs[tid] * invN, msq = cq[tid] * invN;
  float av = a4[(size_t)z * F + tid];
  float var = msq - (2.f * av - av * av) * mean * mean;
  float sc = w4[(size_t)z * F + tid] * rsqrtf(var + EPS);
  float bb = b4[(size_t)z * F + tid];
  float p = p4[z];
  float s = 0.f;
  for (int n = lo + part; n < hi; n += 4) {
    float v = bf2f(x[(size_t)n * F + tid]);
    float y = (v - av * mean) * sc + bb;
    s += (y >= 0.f) ? y : p * y;
  }
  atomicAdd(&g_pool4[((size_t)z * NG + gb) * F + tid], s);
  if (part == 0 && tid == 0) g_cnt4[z * NG + gb] = (float)(hi - lo);
}

// ---------------- conv1d(k=4,s=4) + avgpool(4) ----------------
__global__ void down4_kernel(const float* __restrict__ g_pool4, const float* __restrict__ g_cnt4,
                             const float* __restrict__ cw4, const float* __restrict__ cb4,
                             float* __restrict__ out, int cls0) {
  int z = blockIdx.y;
  int tid = blockIdx.x * blockDim.x + threadIdx.x;
  if (tid >= NG * 16) return;
  int ng = tid >> 4, o = tid & 15;
  const float* g = g_pool4 + ((size_t)z * NG + ng) * F;
  float inv = 1.f / fmaxf(g_cnt4[z * NG + ng], 1.f);
  const float* cw = cw4 + (size_t)z * 4;
  float cb0 = cb4[z];
  float w0 = cw[0], w1 = cw[1], w2 = cw[2], w3 = cw[3];
  float acc = 0.f;
#pragma unroll
  for (int q = 0; q < 4; ++q) {
    const float* gp = g + (o * 4 + q) * 4;
    acc += cb0 + (gp[0] * w0 + gp[1] * w1 + gp[2] * w2 + gp[3] * w3) * inv;
  }
  out[ng * (NCLS * 16) + (cls0 + z) * 16 + o] = acc * 0.25f;
}

extern "C" void kernel_launch(void* const* d_in, const int* in_sizes, int n_in,
                              void* d_out, int out_size, void* d_ws, size_t ws_size,
                              hipStream_t stream) {
  const float* x       = (const float*)d_in[0];
  const int*   edge    = (const int*)d_in[1];
  const int*   batch   = (const int*)d_in[2];
  const float* W1      = (const float*)d_in[3];
  const float* a_src1  = (const float*)d_in[4];
  const float* a_dst1  = (const float*)d_in[5];
  const float* b1      = (const float*)d_in[6];
  const float* W2      = (const float*)d_in[7];
  const float* a_src2  = (const float*)d_in[8];
  const float* a_dst2  = (const float*)d_in[9];
  const float* b2      = (const float*)d_in[10];
  const float* gn_w1   = (const float*)d_in[11];
  const float* gn_b1   = (const float*)d_in[12];
  const float* gn_a1   = (const float*)d_in[13];
  const float* gn_w2   = (const float*)d_in[14];
  const float* gn_b2   = (const float*)d_in[15];
  const float* gn_a2   = (const float*)d_in[16];
  const float* prelu1  = (const float*)d_in[17];
  const float* prelu2  = (const float*)d_in[18];
  const float* conv_w  = (const float*)d_in[19];
  const float* conv_b  = (const float*)d_in[20];
  float* out = (float*)d_out;

  const int E   = in_sizes[1] / (NCLS * 2);
  const int TOT = E + N_NODES;

  auto rb = [](size_t b) -> size_t { return (b + 255) / 256 * 256; };
  auto need = [&](int zw) -> size_t {
    return rb((size_t)N_NODES * T_IN * 2)
         + rb((size_t)zw * N_NODES * F * 2)
         + rb((size_t)zw * N_NODES * F * 2)
         + rb((size_t)NCLS * F * T_IN * 2)
         + rb((size_t)NCLS * F * F * 2)
         + rb((size_t)zw * 2 * N_NODES * HEADS * 4)
         + rb((size_t)NCLS * NBKT * 4)
         + rb((size_t)NCLS * NBKT * 4)
         + rb((size_t)NCLS * 2 * 2 * F * 4)
         + rb((size_t)NCLS * NG * F * 4)
         + rb((size_t)NCLS * NG * 4)
         + rb((size_t)NCLS * PTR_STRIDE * 4)
         + rb((size_t)NCLS * TOT * 2);
  };
  const int zw = (ws_size >= need(4)) ? 4 : 2;

  char* ws = (char*)d_ws;
  size_t off = 0;
  auto alloc = [&](size_t bytes) -> char* {
    char* p = ws + off;
    off += (bytes + 255) / 256 * 256;
    return p;
  };
  ushort* xb      = (ushort*)alloc((size_t)N_NODES * T_IN * 2);
  ushort* hA      = (ushort*)alloc((size_t)zw * N_NODES * F * 2);
  ushort* hB      = (ushort*)alloc((size_t)zw * N_NODES * F * 2);
  ushort* w1t     = (ushort*)alloc((size_t)NCLS * F * T_IN * 2);
  ushort* w2t     = (ushort*)alloc((size_t)NCLS * F * F * 2);
  float*  attn4   = (float*)alloc((size_t)zw * 2 * N_NODES * HEADS * 4);
  char*   zbeg    = ws + off;
  int*    bcnt    = (int*)alloc((size_t)NCLS * NBKT * 4);
  int*    bbase   = (int*)alloc((size_t)NCLS * NBKT * 4);
  float*  colstat = (float*)alloc((size_t)NCLS * 2 * 2 * F * 4);
  float*  g_pool4 = (float*)alloc((size_t)NCLS * NG * F * 4);
  float*  g_cnt4  = (float*)alloc((size_t)NCLS * NG * 4);
  size_t  zlen    = (size_t)((ws + off) - zbeg);
  int* ptr4       = (int*)alloc((size_t)NCLS * PTR_STRIDE * 4);
  ushort* csr4    = (ushort*)alloc((size_t)NCLS * TOT * 2);
  unsigned* bdata = (unsigned*)hA;   // aliases hA (lifetime-disjoint)
  float* cstL1 = colstat;
  float* cstL2 = colstat + (size_t)NCLS * 2 * F;
  (void)n_in; (void)out_size;

  // ---- upfront: one prep kernel + one memset + CSR build ----
  prep_kernel<<<4096, 256, 0, stream>>>(x, xb, W1, w1t, W2, w2t);
  hipMemsetAsync(zbeg, 0, zlen, stream);
  bucketA_kernel<<<dim3((TOT + ECHUNK - 1) / ECHUNK, NCLS), 256, 0, stream>>>(edge, E, bcnt, bdata);
  bscan_kernel<<<1, NBKT, 0, stream>>>(bcnt, bbase);
  bucketB_kernel<<<dim3(NBKT, NCLS), 256, 0, stream>>>(bcnt, bbase, bdata, ptr4, csr4, TOT);

  const dim3 gemm_grid(N_NODES / 128, 2, zw);
  const dim3 agg_grid(N_NODES / 4, zw);
  const dim3 stats_grid(N_NODES / 128, zw);
  const dim3 pool_grid(NG * 4, zw);
  const dim3 down_grid(4, zw);

  for (int it = 0; it < NCLS / zw; ++it) {
    int cls0 = it * zw;
    const int* ptrp = ptr4 + (size_t)cls0 * PTR_STRIDE;
    const ushort* csrp = csr4 + (size_t)cls0 * TOT;

    // ---- layer 1 ----
    gemm4_kernel<false><<<gemm_grid, 256, 0, stream>>>(
        xb, 0, w1t + (size_t)cls0 * F * T_IN,
        a_src1 + (size_t)cls0 * F, a_dst1 + (size_t)cls0 * F,
        nullptr, nullptr, nullptr, nullptr, nullptr, hA, attn4, T_IN);
    agg7_kernel<<<agg_grid, 256, 0, stream>>>(hA, attn4, ptrp, csrp,
                                              b1 + (size_t)cls0 * F, hB, TOT);
    stats4_kernel<<<stats_grid, 256, 0, stream>>>(hB, cstL1 + (size_t)cls0 * 2 * F);

    // ---- layer 2 (GraphNorm+PReLU fused into A-staging) ----
    gemm4_kernel<true><<<gemm_grid, 256, 0, stream>>>(
        hB, (size_t)N_NODES * F, w2t + (size_t)cls0 * F * F,
        a_src2 + (size_t)cls0 * F, a_dst2 + (size_t)cls0 * F,
        cstL1 + (size_t)cls0 * 2 * F, gn_w1 + (size_t)cls0 * F,
        gn_b1 + (size_t)cls0 * F, gn_a1 + (size_t)cls0 * F, prelu1 + cls0,
        hA, attn4, F);
    agg7_kernel<<<agg_grid, 256, 0, stream>>>(hA, attn4, ptrp, csrp,
                                              b2 + (size_t)cls0 * F, hB, TOT);
    stats4_kernel<<<stats_grid, 256, 0, stream>>>(hB, cstL2 + (size_t)cls0 * 2 * F);

    // ---- pool + down ----
    pool_norm4_kernel<<<pool_grid, 256, 0, stream>>>(
        hB, batch + (size_t)cls0 * N_NODES, cstL2 + (size_t)cls0 * 2 * F,
        gn_w2 + (size_t)cls0 * F, gn_b2 + (size_t)cls0 * F, gn_a2 + (size_t)cls0 * F,
        prelu2 + cls0, g_pool4 + (size_t)cls0 * NG * F, g_cnt4 + cls0 * NG);
    down4_kernel<<<down_grid, 256, 0, stream>>>(
        g_pool4 + (size_t)cls0 * NG * F, g_cnt4 + cls0 * NG,
        conv_w + (size_t)cls0 * 4, conv_b + cls0, out, cls0);
  }
}

// Round 15
// 338.354 us; speedup vs baseline: 1.0365x; 1.0042x over previous
//
#include <hip/hip_runtime.h>
#include <math.h>

#define N_NODES 20480
#define T_IN 128
#define F 256
#define HEADS 4
#define HID 64
#define NG 64
#define NCLS 4
#define NEG 0.2f
#define EPS 1e-5f
#define PTR_STRIDE (N_NODES + 64)
#define NBKT 256
#define BKT_NODES 80
#define BKT_CAP 2048
#define ECHUNK 4096

typedef float f32x4 __attribute__((ext_vector_type(4)));
typedef short s16x8 __attribute__((ext_vector_type(8)));
typedef ushort u16x8 __attribute__((ext_vector_type(8)));

static __device__ __forceinline__ ushort f2bf(float f) {
  union { float f; unsigned u; } a; a.f = f;
  unsigned u = a.u;
  unsigned r = (u + 0x7fffu + ((u >> 16) & 1u)) >> 16;
  return (ushort)r;
}
static __device__ __forceinline__ float bf2f(ushort u) {
  union { unsigned u; float f; } a; a.u = ((unsigned)u) << 16;
  return a.f;
}

// ---------------- bucketed CSR build ----------------
__global__ __launch_bounds__(256) void bucketA_kernel(const int* __restrict__ edge, int E,
                                                      int* __restrict__ bcnt,
                                                      unsigned* __restrict__ bdata) {
  int c = blockIdx.y;
  int tot = E + N_NODES;
  int e0 = blockIdx.x * ECHUNK;
  __shared__ int hist[NBKT];
  __shared__ int base[NBKT];
  int tid = threadIdx.x;
  hist[tid] = 0;
  __syncthreads();
  const int* src = edge + (size_t)c * 2 * E;
  const int* dst = src + E;
  unsigned pk[16];
  int bk[16];
#pragma unroll
  for (int i = 0; i < 16; ++i) {
    int e = e0 + i * 256 + tid;
    if (e < tot) {
      int s, d;
      if (e < E) { s = src[e]; d = dst[e]; } else { s = d = e - E; }
      int b = d / BKT_NODES;
      bk[i] = b;
      pk[i] = (unsigned)s | ((unsigned)(d - b * BKT_NODES) << 16);
      atomicAdd(&hist[b], 1);
    } else bk[i] = -1;
  }
  __syncthreads();
  base[tid] = (hist[tid] > 0) ? atomicAdd(&bcnt[c * NBKT + tid], hist[tid]) : 0;
  hist[tid] = 0;
  __syncthreads();
#pragma unroll
  for (int i = 0; i < 16; ++i) {
    if (bk[i] >= 0) {
      int pos = atomicAdd(&hist[bk[i]], 1) + base[bk[i]];
      if (pos < BKT_CAP)
        bdata[((size_t)(c * NBKT + bk[i])) * BKT_CAP + pos] = pk[i];
    }
  }
}

__global__ void bscan_kernel(const int* __restrict__ bcnt, int* __restrict__ bbase) {
  __shared__ int sh[NBKT];
  int t = threadIdx.x;
  for (int c = 0; c < NCLS; ++c) {
    int v = bcnt[c * NBKT + t];
    sh[t] = v;
    __syncthreads();
    for (int off = 1; off < NBKT; off <<= 1) {
      int u = (t >= off) ? sh[t - off] : 0;
      __syncthreads();
      sh[t] += u;
      __syncthreads();
    }
    bbase[c * NBKT + t] = sh[t] - v;
    __syncthreads();
  }
}

__global__ __launch_bounds__(256) void bucketB_kernel(
    const int* __restrict__ bcnt, const int* __restrict__ bbase,
    const unsigned* __restrict__ bdata, int* __restrict__ ptr4,
    ushort* __restrict__ csr4, int TOT_) {
  int b = blockIdx.x, c = blockIdx.y;
  __shared__ int lcount[BKT_NODES + 1];
  __shared__ int lptr[BKT_NODES + 1];
  __shared__ ushort stage[BKT_CAP];
  int tid = threadIdx.x;
  int cnt = min(bcnt[c * NBKT + b], BKT_CAP);
  int base = bbase[c * NBKT + b];
  const unsigned* bd = bdata + ((size_t)(c * NBKT + b)) * BKT_CAP;
  if (tid <= BKT_NODES) lcount[tid] = 0;
  __syncthreads();
  for (int i = tid; i < cnt; i += 256) atomicAdd(&lcount[bd[i] >> 16], 1);
  __syncthreads();
  if (tid == 0) {
    int acc = 0;
    for (int n = 0; n < BKT_NODES; ++n) { lptr[n] = acc; acc += lcount[n]; }
    lptr[BKT_NODES] = acc;
  }
  __syncthreads();
  if (tid < BKT_NODES) ptr4[c * PTR_STRIDE + b * BKT_NODES + tid] = base + lptr[tid];
  if (b == NBKT - 1 && tid == 0) ptr4[c * PTR_STRIDE + N_NODES] = base + lptr[BKT_NODES];
  if (tid <= BKT_NODES) lcount[tid] = 0;
  __syncthreads();
  for (int i = tid; i < cnt; i += 256) {
    unsigned v = bd[i];
    int ld = v >> 16;
    int p = atomicAdd(&lcount[ld], 1) + lptr[ld];
    stage[p] = (ushort)(v & 0xffffu);
  }
  __syncthreads();
  for (int i = tid; i < cnt; i += 256)
    csr4[(size_t)c * TOT_ + base + i] = stage[i];
}

// ---- combined upfront converts: x->bf16, W1^T->bf16, W2^T->bf16 (one launch) ----
__global__ void prep_kernel(const float* __restrict__ x, ushort* __restrict__ xb,
                            const float* __restrict__ W1, ushort* __restrict__ w1t,
                            const float* __restrict__ W2, ushort* __restrict__ w2t) {
  int bid = blockIdx.x;
  int tid = threadIdx.x;
  if (bid < 2560) {
    int idx = bid * 256 + tid;
    float4 v = *(const float4*)(&x[(size_t)idx * 4]);
    ushort4 o;
    o.x = f2bf(v.x); o.y = f2bf(v.y); o.z = f2bf(v.z); o.w = f2bf(v.w);
    *(ushort4*)(&xb[(size_t)idx * 4]) = o;
  } else if (bid < 3072) {
    int t = bid - 2560;
    int c = t >> 7;
    int idx = (t & 127) * 256 + tid;
    int f = idx / T_IN, k = idx - f * T_IN;
    w1t[(size_t)c * F * T_IN + idx] = f2bf(W1[(size_t)c * T_IN * F + (size_t)k * F + f]);
  } else {
    int t = bid - 3072;
    int c = t >> 8;
    int idx = (t & 255) * 256 + tid;
    int f = idx / F, k = idx - f * F;
    w2t[(size_t)c * F * F + idx] = f2bf(W2[(size_t)c * F * F + (size_t)k * F + f]);
  }
}

// ---- MFMA GEMM (z classes) + fused attn epilogue; NORM: fused GraphNorm+PReLU on A ----
template <bool NORM>
__global__ __launch_bounds__(256) void gemm4_kernel(
    const ushort* __restrict__ A, size_t aStride,
    const ushort* __restrict__ Bt,
    const float* __restrict__ asrc, const float* __restrict__ adst,
    const float* __restrict__ cst4, const float* __restrict__ nw4,
    const float* __restrict__ nb4, const float* __restrict__ na4,
    const float* __restrict__ np4,
    ushort* __restrict__ C, float* __restrict__ attn4, int K) {
  int z = blockIdx.z;
  const ushort* Ap = A + (size_t)z * aStride;
  const ushort* Btp = Bt + (size_t)z * F * K;
  ushort* Cp = C + (size_t)z * N_NODES * F;
  float* attn_s = attn4 + (size_t)z * 2 * N_NODES * HEADS;
  float* attn_d = attn_s + N_NODES * HEADS;
  const float* asp = asrc + (size_t)z * F;
  const float* adp = adst + (size_t)z * F;

  __shared__ ushort sA[128][72];
  __shared__ ushort sB[128][72];
  __shared__ float sNsc[256];
  __shared__ float sNsh[256];
  int tid = threadIdx.x;
  float p_ = 0.f;
  if constexpr (NORM) {
    const float* cst = cst4 + (size_t)z * 2 * F;
    const float invN = 1.0f / N_NODES;
    float mean = cst[tid] * invN;
    float msq = cst[F + tid] * invN;
    float av = na4[(size_t)z * F + tid];
    float var = msq - (2.f * av - av * av) * mean * mean;
    float sc = nw4[(size_t)z * F + tid] * rsqrtf(var + EPS);
    sNsc[tid] = sc;
    sNsh[tid] = nb4[(size_t)z * F + tid] - sc * av * mean;
    p_ = np4[z];
    __syncthreads();
  }
  int lane = tid & 63;
  int wave = tid >> 6;
  int wr = (wave >> 1) * 64, wc = (wave & 1) * 64;
  int row0 = blockIdx.x * 128;
  int col0 = blockIdx.y * 128;
  int l15 = lane & 15, l4 = lane >> 4;
  int arow = tid >> 1, aseg = (tid & 1) * 32;
  int bcol = tid & 127, bk = (tid >> 7) * 32;
  f32x4 acc[4][4] = {};
  for (int kt = 0; kt < K; kt += 64) {
    const ushort* ap = Ap + (size_t)(row0 + arow) * K + kt + aseg;
#pragma unroll
    for (int i = 0; i < 4; ++i) {
      if constexpr (NORM) {
        s16x8 av8 = *(const s16x8*)(ap + i * 8);
        s16x8 ov;
#pragma unroll
        for (int kk = 0; kk < 8; ++kk) {
          int col = kt + aseg + i * 8 + kk;
          float xv = bf2f((ushort)av8[kk]);
          float y = xv * sNsc[col] + sNsh[col];
          y = (y >= 0.f) ? y : p_ * y;
          ov[kk] = (short)f2bf(y);
        }
        *(s16x8*)(&sA[arow][aseg + i * 8]) = ov;
      } else {
        *(s16x8*)(&sA[arow][aseg + i * 8]) = *(const s16x8*)(ap + i * 8);
      }
    }
    const ushort* bp = Btp + (size_t)(col0 + bcol) * K + kt + bk;
#pragma unroll
    for (int i = 0; i < 4; ++i)
      *(s16x8*)(&sB[bcol][bk + i * 8]) = *(const s16x8*)(bp + i * 8);
    __syncthreads();
#pragma unroll
    for (int kh = 0; kh < 2; ++kh) {
      s16x8 af[4], bfr[4];
#pragma unroll
      for (int m = 0; m < 4; ++m)
        af[m] = *(const s16x8*)(&sA[wr + m * 16 + l15][kh * 32 + l4 * 8]);
#pragma unroll
      for (int n = 0; n < 4; ++n)
        bfr[n] = *(const s16x8*)(&sB[wc + n * 16 + l15][kh * 32 + l4 * 8]);
#pragma unroll
      for (int m = 0; m < 4; ++m)
#pragma unroll
        for (int n = 0; n < 4; ++n)
          acc[m][n] = __builtin_amdgcn_mfma_f32_16x16x32_bf16(af[m], bfr[n], acc[m][n], 0, 0, 0);
    }
    __syncthreads();
  }

  int hh = (col0 + wc) >> 6;
  float as_n[4], ad_n[4];
#pragma unroll
  for (int n = 0; n < 4; ++n) {
    int cg = col0 + wc + n * 16 + l15;
    as_n[n] = asp[cg];
    ad_n[n] = adp[cg];
  }
#pragma unroll
  for (int m = 0; m < 4; ++m)
#pragma unroll
    for (int r = 0; r < 4; ++r) {
      float ps = acc[m][0][r] * as_n[0] + acc[m][1][r] * as_n[1] +
                 acc[m][2][r] * as_n[2] + acc[m][3][r] * as_n[3];
      float pd = acc[m][0][r] * ad_n[0] + acc[m][1][r] * ad_n[1] +
                 acc[m][2][r] * ad_n[2] + acc[m][3][r] * ad_n[3];
#pragma unroll
      for (int o = 1; o < 16; o <<= 1) {
        ps += __shfl_xor(ps, o);
        pd += __shfl_xor(pd, o);
      }
      if (l15 == 0) {
        int rg = row0 + wr + m * 16 + l4 * 4 + r;
        attn_s[rg * HEADS + hh] = ps;
        attn_d[rg * HEADS + hh] = pd;
      }
    }

#pragma unroll
  for (int m = 0; m < 4; ++m)
#pragma unroll
    for (int n = 0; n < 4; ++n) {
      int rg = row0 + wr + m * 16 + l4 * 4;
      int cg = col0 + wc + n * 16 + l15;
#pragma unroll
      for (int r = 0; r < 4; ++r)
        Cp[(size_t)(rg + r) * F + cg] = f2bf(acc[m][n][r]);
    }
}

// ---- softmax (no max pass) + aggregation: wave per node, prefetch-rotated gather ----
__global__ __launch_bounds__(256) void agg9_kernel(
    const ushort* __restrict__ hfeat4, const float* __restrict__ attn4,
    const int* __restrict__ ptr4, const ushort* __restrict__ csr4,
    const float* __restrict__ bias4, ushort* __restrict__ out4, int TOT_) {
  __shared__ float w_lds[4][64][4];
  __shared__ int s_lds[4][64];
  int z = blockIdx.y;
  int wave = threadIdx.x >> 6, lane = threadIdx.x & 63;
  int node = blockIdx.x * 4 + wave;
  const ushort* hfeat = hfeat4 + (size_t)z * N_NODES * F;
  const float* attn_s = attn4 + (size_t)z * 2 * N_NODES * HEADS;
  const float* attn_d = attn_s + N_NODES * HEADS;
  const int* ptr = ptr4 + (size_t)z * PTR_STRIDE;
  const ushort* csr = csr4 + (size_t)z * TOT_;
  int beg = ptr[node];
  int deg = ptr[node + 1] - beg;
  float4 ad = *(const float4*)(&attn_d[node * 4]);

  int half = lane >> 5, li = lane & 31;
  int ch0 = li * 8;
  int head = li >> 3;
  float acc[8] = {0.f, 0.f, 0.f, 0.f, 0.f, 0.f, 0.f, 0.f};
  float4 dsum = make_float4(0.f, 0.f, 0.f, 0.f);

  for (int c0 = 0; c0 < deg; c0 += 64) {
    int cnt = min(64, deg - c0);
    float4 wv = make_float4(0.f, 0.f, 0.f, 0.f);
    int sE = 0;
    if (c0 + lane < deg) {
      sE = csr[beg + c0 + lane];
      float4 as = *(const float4*)(&attn_s[sE * 4]);
      float vx = as.x + ad.x, vy = as.y + ad.y, vz = as.z + ad.z, vw = as.w + ad.w;
      vx = (vx >= 0.f) ? vx : NEG * vx;
      vy = (vy >= 0.f) ? vy : NEG * vy;
      vz = (vz >= 0.f) ? vz : NEG * vz;
      vw = (vw >= 0.f) ? vw : NEG * vw;
      wv.x = __expf(vx); wv.y = __expf(vy);
      wv.z = __expf(vz); wv.w = __expf(vw);
    }
    dsum.x += wv.x; dsum.y += wv.y; dsum.z += wv.z; dsum.w += wv.w;
    s_lds[wave][lane] = sE;
    *(float4*)(&w_lds[wave][lane][0]) = wv;   // zero weight for inactive lanes

    // prefetch-rotated gather: next edge's 16B load issued before current accumulate
    int cpad = (cnt + 1) & ~1;
    int e = half;
    if (e < cpad) {
      float wcur = w_lds[wave][e][head];
      u16x8 hv = *(const u16x8*)(&hfeat[(size_t)s_lds[wave][e] * F + ch0]);
      for (e += 2; e < cpad; e += 2) {
        float wnext = w_lds[wave][e][head];
        u16x8 hn = *(const u16x8*)(&hfeat[(size_t)s_lds[wave][e] * F + ch0]);
#pragma unroll
        for (int k = 0; k < 8; ++k) acc[k] += wcur * bf2f(hv[k]);
        hv = hn;
        wcur = wnext;
      }
#pragma unroll
      for (int k = 0; k < 8; ++k) acc[k] += wcur * bf2f(hv[k]);
    }
  }
#pragma unroll
  for (int o = 1; o < 64; o <<= 1) {
    dsum.x += __shfl_xor(dsum.x, o);
    dsum.y += __shfl_xor(dsum.y, o);
    dsum.z += __shfl_xor(dsum.z, o);
    dsum.w += __shfl_xor(dsum.w, o);
  }
#pragma unroll
  for (int k = 0; k < 8; ++k) acc[k] += __shfl_xor(acc[k], 32);

  if (half == 0) {
    float dh = (head == 0) ? dsum.x : (head == 1) ? dsum.y : (head == 2) ? dsum.z : dsum.w;
    float inv = 1.f / (dh + 1e-16f);
    u16x8 o;
#pragma unroll
    for (int k = 0; k < 8; ++k)
      o[k] = f2bf(acc[k] * inv + bias4[(size_t)z * F + ch0 + k]);
    *(u16x8*)(&out4[((size_t)z * N_NODES + node) * F + ch0]) = o;
  }
}

// ---------------- GraphNorm stats (bf16 input) ----------------
__global__ void stats4_kernel(const ushort* __restrict__ x4, float* __restrict__ colstat) {
  int z = blockIdx.y;
  const ushort* x = x4 + (size_t)z * N_NODES * F;
  float* cs = colstat + (size_t)z * 2 * F;
  float* cq = cs + F;
  int tid = threadIdx.x;
  int rbeg = blockIdx.x * 128;
  float s = 0.f, s2 = 0.f;
  for (int r = 0; r < 128; ++r) {
    float v = bf2f(x[(size_t)(rbeg + r) * F + tid]);
    s += v;
    s2 += v * v;
  }
  atomicAdd(&cs[tid], s);
  atomicAdd(&cq[tid], s2);
}

// ---------------- fused GraphNorm + PReLU + mean pool ----------------
__device__ __forceinline__ int lower_bound_dev(const int* __restrict__ arr, int n, int key) {
  int lo = 0, hi = n;
  while (lo < hi) {
    int mid = (lo + hi) >> 1;
    if (arr[mid] < key) lo = mid + 1; else hi = mid;
  }
  return lo;
}

__global__ void pool_norm4_kernel(const ushort* __restrict__ x4, const int* __restrict__ batch4,
                                  const float* __restrict__ colstat, const float* __restrict__ w4,
                                  const float* __restrict__ b4, const float* __restrict__ a4,
                                  const float* __restrict__ p4, float* __restrict__ g_pool4,
                                  float* __restrict__ g_cnt4) {
  int z = blockIdx.y;
  int gb = blockIdx.x >> 2, part = blockIdx.x & 3;
  int tid = threadIdx.x;
  const ushort* x = x4 + (size_t)z * N_NODES * F;
  const int* batch = batch4 + (size_t)z * N_NODES;
  const float* cs = colstat + (size_t)z * 2 * F;
  const float* cq = cs + F;
  int lo = lower_bound_dev(batch, N_NODES, gb);
  int hi = lower_bound_dev(batch, N_NODES, gb + 1);
  const float invN = 1.0f / N_NODES;
  float mean = cs[tid] * invN, msq = cq[tid] * invN;
  float av = a4[(size_t)z * F + tid];
  float var = msq - (2.f * av - av * av) * mean * mean;
  float sc = w4[(size_t)z * F + tid] * rsqrtf(var + EPS);
  float bb = b4[(size_t)z * F + tid];
  float p = p4[z];
  float s = 0.f;
  for (int n = lo + part; n < hi; n += 4) {
    float v = bf2f(x[(size_t)n * F + tid]);
    float y = (v - av * mean) * sc + bb;
    s += (y >= 0.f) ? y : p * y;
  }
  atomicAdd(&g_pool4[((size_t)z * NG + gb) * F + tid], s);
  if (part == 0 && tid == 0) g_cnt4[z * NG + gb] = (float)(hi - lo);
}

// ---------------- conv1d(k=4,s=4) + avgpool(4) ----------------
__global__ void down4_kernel(const float* __restrict__ g_pool4, const float* __restrict__ g_cnt4,
                             const float* __restrict__ cw4, const float* __restrict__ cb4,
                             float* __restrict__ out, int cls0) {
  int z = blockIdx.y;
  int tid = blockIdx.x * blockDim.x + threadIdx.x;
  if (tid >= NG * 16) return;
  int ng = tid >> 4, o = tid & 15;
  const float* g = g_pool4 + ((size_t)z * NG + ng) * F;
  float inv = 1.f / fmaxf(g_cnt4[z * NG + ng], 1.f);
  const float* cw = cw4 + (size_t)z * 4;
  float cb0 = cb4[z];
  float w0 = cw[0], w1 = cw[1], w2 = cw[2], w3 = cw[3];
  float acc = 0.f;
#pragma unroll
  for (int q = 0; q < 4; ++q) {
    const float* gp = g + (o * 4 + q) * 4;
    acc += cb0 + (gp[0] * w0 + gp[1] * w1 + gp[2] * w2 + gp[3] * w3) * inv;
  }
  out[ng * (NCLS * 16) + (cls0 + z) * 16 + o] = acc * 0.25f;
}

extern "C" void kernel_launch(void* const* d_in, const int* in_sizes, int n_in,
                              void* d_out, int out_size, void* d_ws, size_t ws_size,
                              hipStream_t stream) {
  const float* x       = (const float*)d_in[0];
  const int*   edge    = (const int*)d_in[1];
  const int*   batch   = (const int*)d_in[2];
  const float* W1      = (const float*)d_in[3];
  const float* a_src1  = (const float*)d_in[4];
  const float* a_dst1  = (const float*)d_in[5];
  const float* b1      = (const float*)d_in[6];
  const float* W2      = (const float*)d_in[7];
  const float* a_src2  = (const float*)d_in[8];
  const float* a_dst2  = (const float*)d_in[9];
  const float* b2      = (const float*)d_in[10];
  const float* gn_w1   = (const float*)d_in[11];
  const float* gn_b1   = (const float*)d_in[12];
  const float* gn_a1   = (const float*)d_in[13];
  const float* gn_w2   = (const float*)d_in[14];
  const float* gn_b2   = (const float*)d_in[15];
  const float* gn_a2   = (const float*)d_in[16];
  const float* prelu1  = (const float*)d_in[17];
  const float* prelu2  = (const float*)d_in[18];
  const float* conv_w  = (const float*)d_in[19];
  const float* conv_b  = (const float*)d_in[20];
  float* out = (float*)d_out;

  const int E   = in_sizes[1] / (NCLS * 2);
  const int TOT = E + N_NODES;

  auto rb = [](size_t b) -> size_t { return (b + 255) / 256 * 256; };
  auto need = [&](int zw) -> size_t {
    return rb((size_t)N_NODES * T_IN * 2)
         + rb((size_t)zw * N_NODES * F * 2)
         + rb((size_t)zw * N_NODES * F * 2)
         + rb((size_t)NCLS * F * T_IN * 2)
         + rb((size_t)NCLS * F * F * 2)
         + rb((size_t)zw * 2 * N_NODES * HEADS * 4)
         + rb((size_t)NCLS * NBKT * 4)
         + rb((size_t)NCLS * NBKT * 4)
         + rb((size_t)NCLS * 2 * 2 * F * 4)
         + rb((size_t)NCLS * NG * F * 4)
         + rb((size_t)NCLS * NG * 4)
         + rb((size_t)NCLS * PTR_STRIDE * 4)
         + rb((size_t)NCLS * TOT * 2);
  };
  const int zw = (ws_size >= need(4)) ? 4 : 2;

  char* ws = (char*)d_ws;
  size_t off = 0;
  auto alloc = [&](size_t bytes) -> char* {
    char* p = ws + off;
    off += (bytes + 255) / 256 * 256;
    return p;
  };
  ushort* xb      = (ushort*)alloc((size_t)N_NODES * T_IN * 2);
  ushort* hA      = (ushort*)alloc((size_t)zw * N_NODES * F * 2);
  ushort* hB      = (ushort*)alloc((size_t)zw * N_NODES * F * 2);
  ushort* w1t     = (ushort*)alloc((size_t)NCLS * F * T_IN * 2);
  ushort* w2t     = (ushort*)alloc((size_t)NCLS * F * F * 2);
  float*  attn4   = (float*)alloc((size_t)zw * 2 * N_NODES * HEADS * 4);
  char*   zbeg    = ws + off;
  int*    bcnt    = (int*)alloc((size_t)NCLS * NBKT * 4);
  int*    bbase   = (int*)alloc((size_t)NCLS * NBKT * 4);
  float*  colstat = (float*)alloc((size_t)NCLS * 2 * 2 * F * 4);
  float*  g_pool4 = (float*)alloc((size_t)NCLS * NG * F * 4);
  float*  g_cnt4  = (float*)alloc((size_t)NCLS * NG * 4);
  size_t  zlen    = (size_t)((ws + off) - zbeg);
  int* ptr4       = (int*)alloc((size_t)NCLS * PTR_STRIDE * 4);
  ushort* csr4    = (ushort*)alloc((size_t)NCLS * TOT * 2);
  unsigned* bdata = (unsigned*)hA;   // aliases hA (lifetime-disjoint)
  float* cstL1 = colstat;
  float* cstL2 = colstat + (size_t)NCLS * 2 * F;
  (void)n_in; (void)out_size;

  // ---- upfront: one prep kernel + one memset + CSR build ----
  prep_kernel<<<4096, 256, 0, stream>>>(x, xb, W1, w1t, W2, w2t);
  hipMemsetAsync(zbeg, 0, zlen, stream);
  bucketA_kernel<<<dim3((TOT + ECHUNK - 1) / ECHUNK, NCLS), 256, 0, stream>>>(edge, E, bcnt, bdata);
  bscan_kernel<<<1, NBKT, 0, stream>>>(bcnt, bbase);
  bucketB_kernel<<<dim3(NBKT, NCLS), 256, 0, stream>>>(bcnt, bbase, bdata, ptr4, csr4, TOT);

  const dim3 gemm_grid(N_NODES / 128, 2, zw);
  const dim3 agg_grid(N_NODES / 4, zw);
  const dim3 stats_grid(N_NODES / 128, zw);
  const dim3 pool_grid(NG * 4, zw);
  const dim3 down_grid(4, zw);

  for (int it = 0; it < NCLS / zw; ++it) {
    int cls0 = it * zw;
    const int* ptrp = ptr4 + (size_t)cls0 * PTR_STRIDE;
    const ushort* csrp = csr4 + (size_t)cls0 * TOT;

    // ---- layer 1 ----
    gemm4_kernel<false><<<gemm_grid, 256, 0, stream>>>(
        xb, 0, w1t + (size_t)cls0 * F * T_IN,
        a_src1 + (size_t)cls0 * F, a_dst1 + (size_t)cls0 * F,
        nullptr, nullptr, nullptr, nullptr, nullptr, hA, attn4, T_IN);
    agg9_kernel<<<agg_grid, 256, 0, stream>>>(hA, attn4, ptrp, csrp,
                                              b1 + (size_t)cls0 * F, hB, TOT);
    stats4_kernel<<<stats_grid, 256, 0, stream>>>(hB, cstL1 + (size_t)cls0 * 2 * F);

    // ---- layer 2 (GraphNorm+PReLU fused into A-staging) ----
    gemm4_kernel<true><<<gemm_grid, 256, 0, stream>>>(
        hB, (size_t)N_NODES * F, w2t + (size_t)cls0 * F * F,
        a_src2 + (size_t)cls0 * F, a_dst2 + (size_t)cls0 * F,
        cstL1 + (size_t)cls0 * 2 * F, gn_w1 + (size_t)cls0 * F,
        gn_b1 + (size_t)cls0 * F, gn_a1 + (size_t)cls0 * F, prelu1 + cls0,
        hA, attn4, F);
    agg9_kernel<<<agg_grid, 256, 0, stream>>>(hA, attn4, ptrp, csrp,
                                              b2 + (size_t)cls0 * F, hB, TOT);
    stats4_kernel<<<stats_grid, 256, 0, stream>>>(hB, cstL2 + (size_t)cls0 * 2 * F);

    // ---- pool + down ----
    pool_norm4_kernel<<<pool_grid, 256, 0, stream>>>(
        hB, batch + (size_t)cls0 * N_NODES, cstL2 + (size_t)cls0 * 2 * F,
        gn_w2 + (size_t)cls0 * F, gn_b2 + (size_t)cls0 * F, gn_a2 + (size_t)cls0 * F,
        prelu2 + cls0, g_pool4 + (size_t)cls0 * NG * F, g_cnt4 + cls0 * NG);
    down4_kernel<<<down_grid, 256, 0, stream>>>(
        g_pool4 + (size_t)cls0 * NG * F, g_cnt4 + cls0 * NG,
        conv_w + (size_t)cls0 * 4, conv_b + cls0, out, cls0);
  }
}